// Round 8
// baseline (9959.762 us; speedup 1.0000x reference)
//
#include <hip/hip_runtime.h>
#include <stdint.h>

// PolicyNetRSNNPB R8 = R7 with the nontemporal-load type fixed (ext_vector
// float4 instead of HIP_vector_type).
//  - XW = x@Wi + bi precomputed into ws (NT stores); in-loop xw is ONE
//    nontemporal 16B load per wave per 2 steps.
//  - Fused dual-gather: layer2(s) and layer1(s+1) share spike list m1(s) ->
//    one list walk, Vr+Wf loads interleaved 16-deep in flight.
//  - 1024 thr, wave = 1 sample, 86KB LDS -> 1 blk/CU -> exact 32 blk/XCD.
//  - One 8-block rendezvous per step, relaxed atomics, no in-loop cache
//    maintenance. Bit-exact add order (absmax 0.0 so far).

typedef unsigned long long u64;
typedef unsigned int u32;
typedef float f32x4 __attribute__((ext_vector_type(4)));

#define NB 512
#define HD 2048
#define NSTEPS 128
#define THREADS 1024
#define NBLK 256
#define COLS 256
#define SPB 16
#define NWPS 32
#define LSTN 2688   // 16 * 2688 * 2B = 86016 B -> forces 1 block/CU

#define DMc 0.8187307530779818f
#define DSc 0.6065306597126334f
#define SMc 0.18126924692201818f

// ---- ws layout ----
#define OFF_M1W 0
#define SZ_M1W (2 * NB * NWPS * 8)               // 256 KB
#define OFF_M2H (OFF_M1W + SZ_M1W)
#define SZ_M2H ((size_t)NSTEPS * NB * NWPS * 8)  // 16 MB
#define OFF_FLAG (OFF_M2H + SZ_M2H)
#define SZ_FLAG (32 * 32 * 4)
#define OFF_CNT (OFF_FLAG + SZ_FLAG)
#define OFF_DONE (OFF_CNT + 64)
#define OFF_XW (((OFF_DONE + 4 + 255) / 256) * 256)
#define SZ_XW ((size_t)64 * NB * HD * 4)         // 256 MB

#define HWREG_XCC_ID (20 | ((4 - 1) << 11))

__global__ void init_ws(u64* __restrict__ m1W, u32* __restrict__ flags,
                        u32* __restrict__ cnt, u32* __restrict__ done) {
  int i = blockIdx.x * 256 + threadIdx.x;
  if (i < 2 * NB * NWPS) m1W[i] = 0ULL;
  if (i < 32 * 32) flags[i] = 0u;
  if (i < 8) cnt[i] = 0u;
  if (i == 0) *done = 0u;
}

// ---------------- XW precompute (R1): XW[t*NB+n][h] = bi[h] + x @ Wi --------
__global__ __launch_bounds__(256) void xw_kernel(
    const float* __restrict__ state, const float* __restrict__ target,
    const float* __restrict__ Wi, const float* __restrict__ bi,
    float* __restrict__ XW) {
  __shared__ float xl[16][128];
  const int tid = threadIdx.x;
  const int col = blockIdx.x * 256 + tid;
  const int r0 = blockIdx.y * 16;

  for (int idx = tid; idx < 16 * 128; idx += 256) {
    int r = idx >> 7, k = idx & 127;
    int gg = r0 + r;
    int t = gg >> 9, n = gg & 511;
    float v = (k < 64) ? state[((size_t)(t * NB + n)) * 64 + k]
                       : target[((size_t)(t * NB + n)) * 64 + (k - 64)];
    xl[r][k] = v;
  }
  __syncthreads();

  float acc[16];
  float b = bi[col];
#pragma unroll
  for (int r = 0; r < 16; ++r) acc[r] = b;
  for (int k = 0; k < 128; ++k) {
    float w = Wi[(size_t)k * HD + col];
#pragma unroll
    for (int r = 0; r < 16; ++r) acc[r] = fmaf(xl[r][k], w, acc[r]);
  }
#pragma unroll
  for (int r = 0; r < 16; ++r)
    __builtin_nontemporal_store(acc[r], &XW[(size_t)(r0 + r) * HD + col]);
}

// bit i of low-16 -> bit 4i
__device__ __forceinline__ u64 spread4(u64 x) {
  x &= 0xffffULL;
  x = (x | (x << 24)) & 0x000000FF000000FFULL;
  x = (x | (x << 12)) & 0x000F000F000F000FULL;
  x = (x | (x << 6))  & 0x0303030303030303ULL;
  x = (x | (x << 3))  & 0x1111111111111111ULL;
  return x;
}

__device__ __forceinline__ u64 pack_word(u64 B0, u64 B1, u64 B2, u64 B3, int q) {
  int sh = q * 16;
  return spread4(B0 >> sh) | (spread4(B1 >> sh) << 1) |
         (spread4(B2 >> sh) << 2) | (spread4(B3 >> sh) << 3);
}

template <bool ATOMIC>
__device__ __forceinline__ int build_list(const u64* __restrict__ mwords,
                                          uint16_t* __restrict__ lstw, int lane) {
  u64 w = 0ULL;
  if (lane < NWPS) {
    if (ATOMIC)
      w = __hip_atomic_load((u64*)&mwords[lane], __ATOMIC_RELAXED,
                            __HIP_MEMORY_SCOPE_AGENT);
    else
      w = mwords[lane];
  }
  int pc = __popcll(w);
  int pre = pc;
#pragma unroll
  for (int off = 1; off < 64; off <<= 1) {
    int v = __shfl_up(pre, off);
    if (lane >= off) pre += v;
  }
  int excl = pre - pc;
  int total = __shfl(pre, 63);
  int kb = lane << 6;
  while (w) {
    int b = __builtin_ctzll(w);
    w &= w - 1;
    lstw[excl++] = (uint16_t)(kb + b);
  }
  asm volatile("s_waitcnt lgkmcnt(0)" ::: "memory");
  return total;
}

// interleaved Vr+Wf gather over one list (ascending k, separate accumulators)
__device__ __forceinline__ void dual_gather(const float* __restrict__ VrB,
                                            const float* __restrict__ WfB,
                                            const uint16_t* __restrict__ lstw,
                                            int total, float aV[4], float aW[4]) {
  for (int j0 = 0; j0 < total; j0 += 8) {
    f32x4 va[8], vb[8];
#pragma unroll
    for (int u = 0; u < 8; ++u) {
      int idx = j0 + u;
      if (idx >= total) idx = j0;
      size_t off = ((size_t)lstw[idx]) << 11;
      va[u] = *(const f32x4*)(VrB + off);
      vb[u] = *(const f32x4*)(WfB + off);
    }
#pragma unroll
    for (int u = 0; u < 8; ++u)
      if (j0 + u < total) {
        aV[0] += va[u].x; aV[1] += va[u].y; aV[2] += va[u].z; aV[3] += va[u].w;
        aW[0] += vb[u].x; aW[1] += vb[u].y; aW[2] += vb[u].z; aW[3] += vb[u].w;
      }
  }
}

__device__ __forceinline__ void single_gather(const float* __restrict__ WB,
                                              const uint16_t* __restrict__ lstw,
                                              int total, float aW[4]) {
  for (int j0 = 0; j0 < total; j0 += 16) {
    f32x4 vb[16];
#pragma unroll
    for (int u = 0; u < 16; ++u) {
      int idx = j0 + u;
      if (idx >= total) idx = j0;
      vb[u] = *(const f32x4*)(WB + (((size_t)lstw[idx]) << 11));
    }
#pragma unroll
    for (int u = 0; u < 16; ++u)
      if (j0 + u < total) {
        aW[0] += vb[u].x; aW[1] += vb[u].y; aW[2] += vb[u].z; aW[3] += vb[u].w;
      }
  }
}

__device__ __forceinline__ u32 lif_update(const float acc[4], float syn[4],
                                          float mem[4], u32 snib) {
  u32 nib = 0;
#pragma unroll
  for (int j = 0; j < 4; ++j) {
    float so = (float)((snib >> j) & 1u);
    float nmem = (DMc * mem[j] + SMc * syn[j]) * (1.0f - so);  // R1 shape
    float nsyn = DSc * syn[j] + acc[j];                         // R1 shape
    mem[j] = nmem;
    syn[j] = nsyn;
    if ((nmem - 1.0f) > 0.0f) nib |= (1u << j);
  }
  return nib;
}

// fallback xw half-chain (only used when ws too small for XW)
__device__ __forceinline__ void xw_half(const float* __restrict__ xrow,
                                        const float* __restrict__ WiCol,
                                        float xw[4]) {
  for (int q = 0; q < 16; ++q) {
    f32x4 xq = *(const f32x4*)(xrow + 4 * q);
    float xv[4] = {xq.x, xq.y, xq.z, xq.w};
#pragma unroll
    for (int kj = 0; kj < 4; ++kj) {
      f32x4 w4 = *(const f32x4*)(WiCol + (size_t)(4 * q + kj) * HD);
      xw[0] = fmaf(xv[kj], w4.x, xw[0]);
      xw[1] = fmaf(xv[kj], w4.y, xw[1]);
      xw[2] = fmaf(xv[kj], w4.z, xw[2]);
      xw[3] = fmaf(xv[kj], w4.w, xw[3]);
    }
  }
}

__global__ __launch_bounds__(THREADS) void rsnn_coop(
    const float* __restrict__ state, const float* __restrict__ target,
    const float* __restrict__ Wi, const float* __restrict__ bi,
    const float* __restrict__ Vr, const float* __restrict__ Wf,
    const float* __restrict__ bf, const float* __restrict__ Wo,
    const float* __restrict__ bo, float* __restrict__ out,
    char* __restrict__ wsb, int use_xw) {
  __shared__ uint16_t lst[16][LSTN];   // 86 KB -> 1 block/CU
  __shared__ int sh_xcd, sh_rank;

  u64* m1W = (u64*)(wsb + OFF_M1W);
  u64* m2H = (u64*)(wsb + OFF_M2H);
  u32* flags = (u32*)(wsb + OFF_FLAG);
  u32* cnt = (u32*)(wsb + OFF_CNT);
  u32* done = (u32*)(wsb + OFF_DONE);
  const float* XW = (const float*)(wsb + OFF_XW);

  const int tid = threadIdx.x;
  const int wv = tid >> 6;
  const int lane = tid & 63;

  if (tid == 0) {
    int xcd = __builtin_amdgcn_s_getreg(HWREG_XCC_ID) & 7;
    sh_xcd = xcd;
    sh_rank = atomicAdd(&cnt[xcd], 1u) & 31;
  }
  __syncthreads();
  const int xcd = sh_xcd;
  const int g = sh_rank;
  const int c0 = xcd * COLS;
  const int smp = g * SPB + wv;

  float bir[4], bfr[4];
#pragma unroll
  for (int j = 0; j < 4; ++j) {
    bir[j] = bi[c0 + lane * 4 + j];
    bfr[j] = bf[c0 + lane * 4 + j];
  }

  float syn1[4], mem1[4], syn2[4], mem2[4];
#pragma unroll
  for (int j = 0; j < 4; ++j) { syn1[j] = 0.f; mem1[j] = 0.f; syn2[j] = 0.f; mem2[j] = 0.f; }
  u32 s1nib = 0u, s2nib = 0u;
  float xwKeep[4];

  const float* VrB = Vr + c0 + lane * 4;
  const float* WfB = Wf + c0 + lane * 4;
  const float* WiC = Wi + c0 + lane * 4;
  const float* XWc = XW + c0 + lane * 4;
  u32* myflag = &flags[g * 32];

  // ---- xw(t=0) ----
  if (use_xw) {
    f32x4 x4 = __builtin_nontemporal_load(
        (const f32x4*)(XWc + (size_t)smp * HD));
    xwKeep[0] = x4.x; xwKeep[1] = x4.y; xwKeep[2] = x4.z; xwKeep[3] = x4.w;
  } else {
#pragma unroll
    for (int j = 0; j < 4; ++j) xwKeep[j] = bir[j];
    xw_half(state + (size_t)smp * 64, WiC, xwKeep);
    xw_half(target + (size_t)smp * 64, WiC + (size_t)64 * HD, xwKeep);
  }

  // ---- prologue: LIF1(0) (no spike rows), publish m1(0) -> buf0 ----
  s1nib = lif_update(xwKeep, syn1, mem1, s1nib);
  {
    u64 B0 = __ballot(s1nib & 1u), B1 = __ballot(s1nib & 2u);
    u64 B2 = __ballot(s1nib & 4u), B3 = __ballot(s1nib & 8u);
    if (lane < 4) {
      u64 wd = pack_word(B0, B1, B2, B3, lane);
      __hip_atomic_store(&m1W[(size_t)smp * NWPS + 4 * xcd + lane], wd,
                         __ATOMIC_RELAXED, __HIP_MEMORY_SCOPE_AGENT);
    }
  }
  __syncthreads();
  if (tid == 0) {
    __hip_atomic_fetch_add(myflag, 1u, __ATOMIC_RELAXED, __HIP_MEMORY_SCOPE_AGENT);
    while (__hip_atomic_load(myflag, __ATOMIC_RELAXED,
                             __HIP_MEMORY_SCOPE_AGENT) < 8u)
      __builtin_amdgcn_s_sleep(2);
  }
  __syncthreads();

  for (int s = 0; s < NSTEPS; ++s) {
    // xw for step s+1 (even steps get a fresh time-slice)
    if (s + 1 < NSTEPS && ((s + 1) & 1) == 0) {
      int t2 = (s + 1) >> 1;
      if (use_xw) {
        f32x4 x4 = __builtin_nontemporal_load(
            (const f32x4*)(XWc + ((size_t)t2 * NB + smp) * HD));
        xwKeep[0] = x4.x; xwKeep[1] = x4.y; xwKeep[2] = x4.z; xwKeep[3] = x4.w;
      } else {
#pragma unroll
        for (int j = 0; j < 4; ++j) xwKeep[j] = bir[j];
        xw_half(state + ((size_t)t2 * NB + smp) * 64, WiC, xwKeep);
        xw_half(target + ((size_t)t2 * NB + smp) * 64, WiC + (size_t)64 * HD,
                xwKeep);
      }
    }

    const u64* m1cur = m1W + (size_t)(s & 1) * NB * NWPS;
    int tot = build_list<true>(m1cur + (size_t)smp * NWPS, &lst[wv][0], lane);

    if (s < NSTEPS - 1) {
      float aV[4] = {xwKeep[0], xwKeep[1], xwKeep[2], xwKeep[3]};
      float aW[4] = {bfr[0], bfr[1], bfr[2], bfr[3]};
      dual_gather(VrB, WfB, &lst[wv][0], tot, aV, aW);

      // LIF2(s), publish m2H(s)
      s2nib = lif_update(aW, syn2, mem2, s2nib);
      {
        u64 B0 = __ballot(s2nib & 1u), B1 = __ballot(s2nib & 2u);
        u64 B2 = __ballot(s2nib & 4u), B3 = __ballot(s2nib & 8u);
        if (lane < 4) {
          u64 wd = pack_word(B0, B1, B2, B3, lane);
          __hip_atomic_store(
              &m2H[((size_t)s * NB + smp) * NWPS + 4 * xcd + lane], wd,
              __ATOMIC_RELAXED, __HIP_MEMORY_SCOPE_AGENT);
        }
      }
      // LIF1(s+1), publish m1(s+1)
      s1nib = lif_update(aV, syn1, mem1, s1nib);
      {
        u64* m1nxt = m1W + (size_t)((s + 1) & 1) * NB * NWPS;
        u64 B0 = __ballot(s1nib & 1u), B1 = __ballot(s1nib & 2u);
        u64 B2 = __ballot(s1nib & 4u), B3 = __ballot(s1nib & 8u);
        if (lane < 4) {
          u64 wd = pack_word(B0, B1, B2, B3, lane);
          __hip_atomic_store(&m1nxt[(size_t)smp * NWPS + 4 * xcd + lane], wd,
                             __ATOMIC_RELAXED, __HIP_MEMORY_SCOPE_AGENT);
        }
      }
      // rendezvous
      __syncthreads();
      if (tid == 0) {
        __hip_atomic_fetch_add(myflag, 1u, __ATOMIC_RELAXED,
                               __HIP_MEMORY_SCOPE_AGENT);
        u32 tgt = 8u * (u32)(s + 2);
        while (__hip_atomic_load(myflag, __ATOMIC_RELAXED,
                                 __HIP_MEMORY_SCOPE_AGENT) < tgt)
          __builtin_amdgcn_s_sleep(2);
      }
      __syncthreads();
    } else {
      // s == 127: layer-2 only
      float aW[4] = {bfr[0], bfr[1], bfr[2], bfr[3]};
      single_gather(WfB, &lst[wv][0], tot, aW);
      s2nib = lif_update(aW, syn2, mem2, s2nib);
      {
        u64 B0 = __ballot(s2nib & 1u), B1 = __ballot(s2nib & 2u);
        u64 B2 = __ballot(s2nib & 4u), B3 = __ballot(s2nib & 8u);
        if (lane < 4) {
          u64 wd = pack_word(B0, B1, B2, B3, lane);
          __hip_atomic_store(
              &m2H[((size_t)s * NB + smp) * NWPS + 4 * xcd + lane], wd,
              __ATOMIC_RELAXED, __HIP_MEMORY_SCOPE_AGENT);
        }
      }
    }
  }

  // ---- final rendezvous (full fence once: replay-stale lines) ----
  __syncthreads();
  if (tid == 0) {
    __threadfence();
    __hip_atomic_fetch_add(done, 1u, __ATOMIC_RELEASE, __HIP_MEMORY_SCOPE_AGENT);
    while (__hip_atomic_load(done, __ATOMIC_RELAXED,
                             __HIP_MEMORY_SCOPE_AGENT) < (u32)NBLK)
      __builtin_amdgcn_s_sleep(8);
    __threadfence();
  }
  __syncthreads();

  // ---- deferred readout: 2 waves/block, wave = one sample ----
  if (wv < 2) {
    const int rsmp = blockIdx.x * 2 + wv;
    const float bor = bo[lane];
    float synr = 0.f, memr = 0.f, roprev = 0.f;
    for (int s = 0; s < NSTEPS; ++s) {
      int total = build_list<false>(m2H + ((size_t)s * NB + rsmp) * NWPS,
                                    &lst[wv][0], lane);
      float a = bor;
      for (int j0 = 0; j0 < total; j0 += 8) {
        float vv[8];
#pragma unroll
        for (int u = 0; u < 8; ++u) {
          int idx = j0 + u;
          if (idx >= total) idx = j0;
          vv[u] = Wo[(((size_t)lst[wv][idx]) << 6) + lane];
        }
#pragma unroll
        for (int u = 0; u < 8; ++u)
          if (j0 + u < total) a += vv[u];
      }
      float nmemr = DMc * memr + SMc * synr;  // R1 shape
      float nsynr = DSc * synr + a;           // R1 shape
      memr = nmemr;
      synr = nsynr;
      if (s & 1) {
        float v = 0.5f * (roprev + nmemr);
        size_t base = ((size_t)(s >> 1) * NB + rsmp) * 32;
        if (lane < 32) out[base + lane] = v;
        else out[(size_t)64 * NB * 32 + base + (lane - 32)] = v;
      } else {
        roprev = nmemr;
      }
    }
  }
}

extern "C" void kernel_launch(void* const* d_in, const int* in_sizes, int n_in,
                              void* d_out, int out_size, void* d_ws, size_t ws_size,
                              hipStream_t stream) {
  const float* state  = (const float*)d_in[0];
  const float* target = (const float*)d_in[1];
  const float* Wi     = (const float*)d_in[2];
  const float* bi     = (const float*)d_in[3];
  const float* Vr     = (const float*)d_in[4];
  const float* Wf     = (const float*)d_in[5];
  const float* bf     = (const float*)d_in[6];
  const float* Wo     = (const float*)d_in[7];
  const float* bo     = (const float*)d_in[8];
  float* out = (float*)d_out;
  char* wsb = (char*)d_ws;

  int use_xw = (ws_size >= OFF_XW + SZ_XW) ? 1 : 0;

  init_ws<<<128, 256, 0, stream>>>((u64*)(wsb + OFF_M1W), (u32*)(wsb + OFF_FLAG),
                                   (u32*)(wsb + OFF_CNT), (u32*)(wsb + OFF_DONE));
  if (use_xw) {
    xw_kernel<<<dim3(8, 2048), 256, 0, stream>>>(state, target, Wi, bi,
                                                 (float*)(wsb + OFF_XW));
  }

  void* args[] = {(void*)&state, (void*)&target, (void*)&Wi, (void*)&bi,
                  (void*)&Vr, (void*)&Wf, (void*)&bf, (void*)&Wo, (void*)&bo,
                  (void*)&out, (void*)&wsb, (void*)&use_xw};
  (void)hipLaunchCooperativeKernel(rsnn_coop, dim3(NBLK), dim3(THREADS), args, 0,
                                   stream);
}

// Round 9
// 3688.272 us; speedup vs baseline: 2.7004x; 2.7004x over previous
//
#include <hip/hip_runtime.h>
#include <stdint.h>

// PolicyNetRSNNPB R9: R5 structure (512 thr, 8 waves/CU, best: 4.2ms) +
// row-packed weights + fused single-walk dual gather.
// R6/R8 lesson: >8 gather waves/CU over-subscribes the exactly-4MB per-XCD
// L2 slice (FETCH 2.5GB -> 14-17GB). Stay at 8 waves.
// New: PK[xcd][k] = [Vr_slice(k)|Wf_slice(k)] (2KB rows, packed once into ws).
// layer2(s) and layer1(s+1) share spike list m1(s) -> ONE walk per step feeds
// both layers from the same 2KB row (co-fetched, co-evicted), halving list
// builds and serial batch chains. Bit-exact add order preserved.

typedef unsigned long long u64;
typedef unsigned int u32;
typedef float f32x4 __attribute__((ext_vector_type(4)));

#define NB 512
#define HD 2048
#define NSTEPS 128
#define THREADS 512
#define NBLK 256
#define COLS 256
#define SPB 16
#define NWPS 32
#define LSTN 1024

#define DMc 0.8187307530779818f
#define DSc 0.6065306597126334f
#define SMc 0.18126924692201818f

// ---- ws layout ----
#define OFF_M1W 0
#define SZ_M1W (2 * NB * NWPS * 8)               // 256 KB
#define OFF_M2H (OFF_M1W + SZ_M1W)
#define SZ_M2H ((size_t)NSTEPS * NB * NWPS * 8)  // 16 MB
#define OFF_FLAG (OFF_M2H + SZ_M2H)
#define SZ_FLAG (32 * 32 * 4)
#define OFF_CNT (OFF_FLAG + SZ_FLAG)
#define OFF_DONE (OFF_CNT + 64)
#define OFF_PK (((size_t)(OFF_DONE + 4) + 4194303) & ~(size_t)4194303)
#define SZ_PK ((size_t)8 * HD * 512 * 4)         // 32 MB

#define HWREG_XCC_ID (20 | ((4 - 1) << 11))

__global__ void init_ws(u64* __restrict__ m1W, u32* __restrict__ flags,
                        u32* __restrict__ cnt, u32* __restrict__ done) {
  int i = blockIdx.x * 256 + threadIdx.x;
  if (i < 2 * NB * NWPS) m1W[i] = 0ULL;
  if (i < 32 * 32) flags[i] = 0u;
  if (i < 8) cnt[i] = 0u;
  if (i == 0) *done = 0u;
}

// PK[xcd][k][0..255] = Vr[k][xcd*256..], PK[xcd][k][256..511] = Wf[k][...]
__global__ __launch_bounds__(256) void pack_kernel(
    const float* __restrict__ Vr, const float* __restrict__ Wf,
    float* __restrict__ PK) {
  const int k = blockIdx.x;
  const int tid = threadIdx.x;
  for (int c = tid; c < HD; c += 256) {
    int xcd = c >> 8, cc = c & 255;
    size_t base = ((size_t)xcd * HD + k) * 512;
    __builtin_nontemporal_store(Vr[(size_t)k * HD + c], &PK[base + cc]);
    __builtin_nontemporal_store(Wf[(size_t)k * HD + c], &PK[base + 256 + cc]);
  }
}

// bit i of low-16 -> bit 4i
__device__ __forceinline__ u64 spread4(u64 x) {
  x &= 0xffffULL;
  x = (x | (x << 24)) & 0x000000FF000000FFULL;
  x = (x | (x << 12)) & 0x000F000F000F000FULL;
  x = (x | (x << 6))  & 0x0303030303030303ULL;
  x = (x | (x << 3))  & 0x1111111111111111ULL;
  return x;
}

__device__ __forceinline__ u64 pack_word(u64 B0, u64 B1, u64 B2, u64 B3, int q) {
  int sh = q * 16;
  return spread4(B0 >> sh) | (spread4(B1 >> sh) << 1) |
         (spread4(B2 >> sh) << 2) | (spread4(B3 >> sh) << 3);
}

template <bool ATOMIC>
__device__ __forceinline__ int build_list(const u64* __restrict__ mwords,
                                          uint16_t* __restrict__ lstw, int lane) {
  u64 w = 0ULL;
  if (lane < NWPS) {
    if (ATOMIC)
      w = __hip_atomic_load((u64*)&mwords[lane], __ATOMIC_RELAXED,
                            __HIP_MEMORY_SCOPE_AGENT);
    else
      w = mwords[lane];
  }
  int pc = __popcll(w);
  int pre = pc;
#pragma unroll
  for (int off = 1; off < 64; off <<= 1) {
    int v = __shfl_up(pre, off);
    if (lane >= off) pre += v;
  }
  int excl = pre - pc;
  int total = __shfl(pre, 63);
  int kb = lane << 6;
  while (w) {
    int b = __builtin_ctzll(w);
    w &= w - 1;
    if (excl < LSTN) lstw[excl] = (uint16_t)(kb + b);
    ++excl;
  }
  asm volatile("s_waitcnt lgkmcnt(0)" ::: "memory");
  return total < LSTN ? total : LSTN;
}

// one walk, both layers: aV += PK[k][lane*4..] (Vr), aW += PK[k][256+..] (Wf)
__device__ __forceinline__ void dual_gather_pk(const float* __restrict__ PKb,
                                               const uint16_t* __restrict__ lstw,
                                               int total, float aV[4],
                                               float aW[4]) {
  for (int j0 = 0; j0 < total; j0 += 8) {
    f32x4 va[8], vb[8];
#pragma unroll
    for (int u = 0; u < 8; ++u) {
      int idx = j0 + u;
      if (idx >= total) idx = j0;
      size_t off = ((size_t)lstw[idx]) << 9;
      va[u] = *(const f32x4*)(PKb + off);
      vb[u] = *(const f32x4*)(PKb + off + 256);
    }
#pragma unroll
    for (int u = 0; u < 8; ++u)
      if (j0 + u < total) {
        aV[0] += va[u].x; aV[1] += va[u].y; aV[2] += va[u].z; aV[3] += va[u].w;
        aW[0] += vb[u].x; aW[1] += vb[u].y; aW[2] += vb[u].z; aW[3] += vb[u].w;
      }
  }
}

__device__ __forceinline__ u32 lif_update(const float acc[4], float syn[4],
                                          float mem[4], u32 snib) {
  u32 nib = 0;
#pragma unroll
  for (int j = 0; j < 4; ++j) {
    float so = (float)((snib >> j) & 1u);
    float nmem = (DMc * mem[j] + SMc * syn[j]) * (1.0f - so);  // R1 shape
    float nsyn = DSc * syn[j] + acc[j];                         // R1 shape
    mem[j] = nmem;
    syn[j] = nsyn;
    if ((nmem - 1.0f) > 0.0f) nib |= (1u << j);
  }
  return nib;
}

__global__ __launch_bounds__(THREADS) void rsnn_coop(
    const float* __restrict__ state, const float* __restrict__ target,
    const float* __restrict__ Wi, const float* __restrict__ bi,
    const float* __restrict__ Vr, const float* __restrict__ Wf,
    const float* __restrict__ bf, const float* __restrict__ Wo,
    const float* __restrict__ bo, float* __restrict__ out,
    char* __restrict__ wsb) {
  __shared__ float Wi_s[128 * COLS];   // 128 KB
  __shared__ uint16_t lst[8][LSTN];    // 16 KB -> total ~145 KB -> 1 blk/CU
  __shared__ int sh_xcd, sh_rank;

  u64* m1W = (u64*)(wsb + OFF_M1W);
  u64* m2H = (u64*)(wsb + OFF_M2H);
  u32* flags = (u32*)(wsb + OFF_FLAG);
  u32* cnt = (u32*)(wsb + OFF_CNT);
  u32* done = (u32*)(wsb + OFF_DONE);
  const float* PK = (const float*)(wsb + OFF_PK);

  const int tid = threadIdx.x;
  const int wv = tid >> 6;      // 0..7, wave = 2 samples
  const int lane = tid & 63;    // lane = 4 columns

  if (tid == 0) {
    int xcd = __builtin_amdgcn_s_getreg(HWREG_XCC_ID) & 7;
    sh_xcd = xcd;
    sh_rank = atomicAdd(&cnt[xcd], 1u) & 31;
  }
  __syncthreads();
  const int xcd = sh_xcd;
  const int g = sh_rank;
  const int c0 = xcd * COLS;
  const int sA = g * SPB + wv * 2, sB = sA + 1;

  // stage Wi column slice into LDS
  for (int i = tid; i < 128 * COLS; i += THREADS) {
    int k = i >> 8, c = i & 255;
    Wi_s[i] = Wi[(size_t)k * HD + c0 + c];
  }

  float bir[4], bfr[4];
#pragma unroll
  for (int j = 0; j < 4; ++j) {
    bir[j] = bi[c0 + lane * 4 + j];
    bfr[j] = bf[c0 + lane * 4 + j];
  }

  float syn1[2][4], mem1[2][4], syn2[2][4], mem2[2][4];
#pragma unroll
  for (int r = 0; r < 2; ++r)
#pragma unroll
    for (int j = 0; j < 4; ++j) {
      syn1[r][j] = 0.f; mem1[r][j] = 0.f; syn2[r][j] = 0.f; mem2[r][j] = 0.f;
    }
  u32 s1nib[2] = {0u, 0u}, s2nib[2] = {0u, 0u};
  float xwA[4], xwB[4];

  const float* PKb = PK + (size_t)xcd * HD * 512 + lane * 4;
  u32* myflag = &flags[g * 32];

  __syncthreads();  // Wi_s ready

  // ---- xw(t) for samples A,B from Wi_s (k-ascending fmaf, bit-exact) ----
  auto compute_xw = [&](int t2) {
#pragma unroll
    for (int j = 0; j < 4; ++j) { xwA[j] = bir[j]; xwB[j] = bir[j]; }
#pragma unroll
    for (int half = 0; half < 2; ++half) {
      const float* pA = (half ? target : state) + ((size_t)t2 * NB + sA) * 64;
      const float* pB = (half ? target : state) + ((size_t)t2 * NB + sB) * 64;
      for (int q = 0; q < 16; ++q) {
        f32x4 xa = *(const f32x4*)(pA + 4 * q);
        f32x4 xb = *(const f32x4*)(pB + 4 * q);
        float xav[4] = {xa.x, xa.y, xa.z, xa.w};
        float xbv[4] = {xb.x, xb.y, xb.z, xb.w};
#pragma unroll
        for (int kj = 0; kj < 4; ++kj) {
          const f32x4 w4 =
              *(const f32x4*)&Wi_s[(half * 64 + 4 * q + kj) * COLS + lane * 4];
          xwA[0] = fmaf(xav[kj], w4.x, xwA[0]);
          xwA[1] = fmaf(xav[kj], w4.y, xwA[1]);
          xwA[2] = fmaf(xav[kj], w4.z, xwA[2]);
          xwA[3] = fmaf(xav[kj], w4.w, xwA[3]);
          xwB[0] = fmaf(xbv[kj], w4.x, xwB[0]);
          xwB[1] = fmaf(xbv[kj], w4.y, xwB[1]);
          xwB[2] = fmaf(xbv[kj], w4.z, xwB[2]);
          xwB[3] = fmaf(xbv[kj], w4.w, xwB[3]);
        }
      }
    }
  };

  // ---- prologue: xw(0); LIF1(0) (no spikes); publish m1(0); rendezvous ----
  compute_xw(0);
#pragma unroll
  for (int r = 0; r < 2; ++r) {
    const int smp = r ? sB : sA;
    s1nib[r] = lif_update(r ? xwB : xwA, syn1[r], mem1[r], s1nib[r]);
    u64 B0 = __ballot(s1nib[r] & 1u), B1 = __ballot(s1nib[r] & 2u);
    u64 B2 = __ballot(s1nib[r] & 4u), B3 = __ballot(s1nib[r] & 8u);
    if (lane < 4) {
      u64 wd = pack_word(B0, B1, B2, B3, lane);
      __hip_atomic_store(&m1W[(size_t)smp * NWPS + 4 * xcd + lane], wd,
                         __ATOMIC_RELAXED, __HIP_MEMORY_SCOPE_AGENT);
    }
  }
  __syncthreads();
  if (tid == 0) {
    __hip_atomic_fetch_add(myflag, 1u, __ATOMIC_RELAXED, __HIP_MEMORY_SCOPE_AGENT);
    while (__hip_atomic_load(myflag, __ATOMIC_RELAXED,
                             __HIP_MEMORY_SCOPE_AGENT) < 8u)
      __builtin_amdgcn_s_sleep(2);
  }
  __syncthreads();

  // ---- main loop: per step ONE list walk feeds layer2(s) AND layer1(s+1) ----
  for (int s = 0; s < NSTEPS; ++s) {
    // xw for step s+1 (fresh slice when s+1 is even; else keep)
    if (s + 1 < NSTEPS && ((s + 1) & 1) == 0) compute_xw((s + 1) >> 1);

    const u64* m1cur = m1W + (size_t)(s & 1) * NB * NWPS;
    u64* m1nxt = m1W + (size_t)((s + 1) & 1) * NB * NWPS;
    const bool last = (s == NSTEPS - 1);

#pragma unroll
    for (int r = 0; r < 2; ++r) {
      const int smp = r ? sB : sA;
      int tot = build_list<true>(m1cur + (size_t)smp * NWPS, &lst[wv][0], lane);

      float aV[4], aW[4];
#pragma unroll
      for (int j = 0; j < 4; ++j) {
        aV[j] = r ? xwB[j] : xwA[j];
        aW[j] = bfr[j];
      }
      dual_gather_pk(PKb, &lst[wv][0], tot, aV, aW);

      // LIF2(s) -> m2 history
      s2nib[r] = lif_update(aW, syn2[r], mem2[r], s2nib[r]);
      {
        u64 B0 = __ballot(s2nib[r] & 1u), B1 = __ballot(s2nib[r] & 2u);
        u64 B2 = __ballot(s2nib[r] & 4u), B3 = __ballot(s2nib[r] & 8u);
        if (lane < 4) {
          u64 wd = pack_word(B0, B1, B2, B3, lane);
          __hip_atomic_store(
              &m2H[((size_t)s * NB + smp) * NWPS + 4 * xcd + lane], wd,
              __ATOMIC_RELAXED, __HIP_MEMORY_SCOPE_AGENT);
        }
      }
      // LIF1(s+1) -> m1 next buffer
      if (!last) {
        s1nib[r] = lif_update(aV, syn1[r], mem1[r], s1nib[r]);
        u64 B0 = __ballot(s1nib[r] & 1u), B1 = __ballot(s1nib[r] & 2u);
        u64 B2 = __ballot(s1nib[r] & 4u), B3 = __ballot(s1nib[r] & 8u);
        if (lane < 4) {
          u64 wd = pack_word(B0, B1, B2, B3, lane);
          __hip_atomic_store(&m1nxt[(size_t)smp * NWPS + 4 * xcd + lane], wd,
                             __ATOMIC_RELAXED, __HIP_MEMORY_SCOPE_AGENT);
        }
      }
    }

    if (!last) {
      __syncthreads();
      if (tid == 0) {
        __hip_atomic_fetch_add(myflag, 1u, __ATOMIC_RELAXED,
                               __HIP_MEMORY_SCOPE_AGENT);
        u32 tgt = 8u * (u32)(s + 2);
        while (__hip_atomic_load(myflag, __ATOMIC_RELAXED,
                                 __HIP_MEMORY_SCOPE_AGENT) < tgt)
          __builtin_amdgcn_s_sleep(2);
      }
      __syncthreads();
    }
  }

  // ---- final rendezvous (full fence once: replay-stale lines) ----
  __syncthreads();
  if (tid == 0) {
    __threadfence();
    __hip_atomic_fetch_add(done, 1u, __ATOMIC_RELEASE, __HIP_MEMORY_SCOPE_AGENT);
    while (__hip_atomic_load(done, __ATOMIC_RELAXED,
                             __HIP_MEMORY_SCOPE_AGENT) < (u32)NBLK)
      __builtin_amdgcn_s_sleep(8);
    __threadfence();
  }
  __syncthreads();

  // ---- deferred readout: 2 waves/block, wave = one sample ----
  if (wv < 2) {
    const int rsmp = blockIdx.x * 2 + wv;
    const float bor = bo[lane];
    float synr = 0.f, memr = 0.f, roprev = 0.f;
    for (int s = 0; s < NSTEPS; ++s) {
      int total = build_list<false>(m2H + ((size_t)s * NB + rsmp) * NWPS,
                                    &lst[wv][0], lane);
      float a = bor;
      for (int j0 = 0; j0 < total; j0 += 8) {
        float vv[8];
#pragma unroll
        for (int u = 0; u < 8; ++u) {
          int idx = j0 + u;
          if (idx >= total) idx = j0;
          vv[u] = Wo[(((size_t)lst[wv][idx]) << 6) + lane];
        }
#pragma unroll
        for (int u = 0; u < 8; ++u)
          if (j0 + u < total) a += vv[u];
      }
      float nmemr = DMc * memr + SMc * synr;  // R1 shape
      float nsynr = DSc * synr + a;           // R1 shape
      memr = nmemr;
      synr = nsynr;
      if (s & 1) {
        float v = 0.5f * (roprev + nmemr);
        size_t base = ((size_t)(s >> 1) * NB + rsmp) * 32;
        if (lane < 32) out[base + lane] = v;
        else out[(size_t)64 * NB * 32 + base + (lane - 32)] = v;
      } else {
        roprev = nmemr;
      }
    }
  }
}

extern "C" void kernel_launch(void* const* d_in, const int* in_sizes, int n_in,
                              void* d_out, int out_size, void* d_ws, size_t ws_size,
                              hipStream_t stream) {
  const float* state  = (const float*)d_in[0];
  const float* target = (const float*)d_in[1];
  const float* Wi     = (const float*)d_in[2];
  const float* bi     = (const float*)d_in[3];
  const float* Vr     = (const float*)d_in[4];
  const float* Wf     = (const float*)d_in[5];
  const float* bf     = (const float*)d_in[6];
  const float* Wo     = (const float*)d_in[7];
  const float* bo     = (const float*)d_in[8];
  float* out = (float*)d_out;
  char* wsb = (char*)d_ws;

  init_ws<<<128, 256, 0, stream>>>((u64*)(wsb + OFF_M1W), (u32*)(wsb + OFF_FLAG),
                                   (u32*)(wsb + OFF_CNT), (u32*)(wsb + OFF_DONE));
  pack_kernel<<<HD, 256, 0, stream>>>(Vr, Wf, (float*)(wsb + OFF_PK));

  void* args[] = {(void*)&state, (void*)&target, (void*)&Wi, (void*)&bi,
                  (void*)&Vr, (void*)&Wf, (void*)&bf, (void*)&Wo, (void*)&bo,
                  (void*)&out, (void*)&wsb};
  (void)hipLaunchCooperativeKernel(rsnn_coop, dim3(NBLK), dim3(THREADS), args, 0,
                                   stream);
}